// Round 9
// baseline (246.273 us; speedup 1.0000x reference)
//
#include <hip/hip_runtime.h>
#include <stdint.h>

#define OUT_HW    14
#define NBINS     196               // 14*14
#define C_TOTAL   256
#define C_PER_BLK 64
#define NQUADS    (C_PER_BLK / 4)   // 16 channel-quads per block
#define NBOXES    512
#define BUFQ      1280              // 16B cells per buffer (strict footprint bound ~1000)
#define QWORDS    (4 * BUFQ)        // 5120 words = 20 KB per buffer (2 bufs = 40 KB)
#define MAXC      5                 // BUFQ / 256 cells per thread

__device__ __forceinline__ void axis_entry(float coord, float L,
                                           int& lo, int& hi, float& wlo, float& whi) {
    // torchvision ROIAlign bilinear edge handling
    const bool valid = (coord >= -1.0f) && (coord <= L);
    const float c   = fminf(fmaxf(coord, 0.0f), L - 1.0f);
    const float flo = floorf(c);
    const float fhi = fminf(flo + 1.0f, L - 1.0f);
    whi = c - flo;
    wlo = 1.0f - whi;
    if (!valid) { wlo = 0.0f; whi = 0.0f; }
    lo = (int)flo;
    hi = (int)fhi;
}

__global__ __launch_bounds__(256, 4) void roi_pool_kernel(
    const float* __restrict__ x0, const float* __restrict__ x1,
    const float* __restrict__ x2, const float* __restrict__ x3,
    const float* __restrict__ boxes, float* __restrict__ out)
{
    __shared__ float tile[2][QWORDS];   // 2 x 20 KB = 40 KB -> 4 blocks/CU

    const int m    = blockIdx.x;   // box
    const int cblk = blockIdx.y;   // 64-channel chunk
    const int tid  = threadIdx.x;

    // ---- block-uniform box/level setup ----
    const float bxi = boxes[m*5+0];
    const float bx0 = boxes[m*5+1];
    const float by0 = boxes[m*5+2];
    const float bx1 = boxes[m*5+3];
    const float by1 = boxes[m*5+4];

    const float sz = sqrtf((bx1 - bx0) * (by1 - by0));
    int lvl = (int)floorf(4.0f + log2f(sz * (1.0f/224.0f) + 1e-8f));
    lvl = min(max(lvl, 2), 5) - 2;

    const float scales[4] = {0.25f, 0.125f, 0.0625f, 0.03125f};
    const int   dims[4]   = {256, 128, 64, 32};
    const float scale = scales[lvl];
    const int   W  = dims[lvl];
    const int   HW = W * W;
    const float Lf = (float)W;
    const float* feat = (lvl == 0) ? x0 : (lvl == 1) ? x1 : (lvl == 2) ? x2 : x3;
    const int bidx = (int)bxi;

    const float rx0 = bx0*scale - 0.5f;
    const float ry0 = by0*scale - 0.5f;
    const float binw = (bx1*scale - 0.5f - rx0) * (1.0f/14.0f);
    const float binh = (by1*scale - 0.5f - ry0) * (1.0f/14.0f);

    // ---- footprint extents (samples are monotone; first lo / last hi) ----
    int ymin, ymax, xmin, xmax;
    {
        int lo, hi; float a, b;
        axis_entry(ry0 +  0.25f*binh, Lf, lo, hi, a, b); ymin = lo;
        axis_entry(ry0 + 13.75f*binh, Lf, lo, hi, a, b); ymax = hi;
        axis_entry(rx0 +  0.25f*binw, Lf, lo, hi, a, b); xmin = lo;
        axis_entry(rx0 + 13.75f*binw, Lf, lo, hi, a, b); xmax = hi;
    }
    const int TW = (xmax - xmin + 1) | 1;          // ODD cell stride: rotates bank phase per row
    int NR = ymax - ymin + 1;                      // tile rows
    if (NR * TW > BUFQ) NR = BUFQ / TW;            // safety cap (analysis: never triggers)
    const int TC = NR * TW;                        // cells (16B each) per quad tile

    // ---- per-thread cell slots (constant across quads); pure row-major layout ----
    int  gw[MAXC], lw[MAXC];
    bool cv[MAXC];
    #pragma unroll
    for (int s = 0; s < MAXC; ++s) {
        const int cell = tid + (s << 8);
        cv[s] = (cell < TC);
        const int cl = min(cell, TC - 1);
        const int r  = cl / TW;
        const int c  = cl - r * TW;
        gw[s] = min((ymin + r) * W + xmin + c, HW - 1);   // clamp: pad cols stay in-plane
        lw[s] = cl << 2;                                   // linear dest word (cell*4)
    }

    // ---- per-thread tap setup (bin = thread) ----
    const bool active = (tid < NBINS);
    const int  t  = active ? tid : (NBINS - 1);
    const int  ph = t / OUT_HW;
    const int  pw = t - ph * OUT_HW;

    int yl0, yh0, yl1, yh1, xl0, xh0, xl1, xh1;
    float wy0, wy1, wy2, wy3, wx0, wx1, wx2, wx3;
    axis_entry(ry0 + ((float)ph + 0.25f)*binh, Lf, yl0, yh0, wy0, wy1);
    axis_entry(ry0 + ((float)ph + 0.75f)*binh, Lf, yl1, yh1, wy2, wy3);
    axis_entry(rx0 + ((float)pw + 0.25f)*binw, Lf, xl0, xh0, wx0, wx1);
    axis_entry(rx0 + ((float)pw + 0.75f)*binw, Lf, xl1, xh1, wx2, wx3);
    wy0 *= 0.25f; wy1 *= 0.25f; wy2 *= 0.25f; wy3 *= 0.25f;  // fold 2x2 mean
    const float wyv[4] = { wy0, wy1, wy2, wy3 };

    const int sr[4] = { yl0 - ymin, yh0 - ymin, yl1 - ymin, yh1 - ymin };
    const int sc[4] = { xl0 - xmin, xh0 - xmin, xl1 - xmin, xh1 - xmin };

    int wq[16];   // tap cell indices (16B units), row-major
    #pragma unroll
    for (int i = 0; i < 4; ++i) {
        #pragma unroll
        for (int j = 0; j < 4; ++j) {
            wq[i*4 + j] = min(sr[i] * TW + sc[j], TC - 1);
        }
    }

    const float* fb = feat + ((size_t)bidx * C_TOTAL + (size_t)cblk * C_PER_BLK) * HW;
    float* ob = out + ((size_t)m * C_TOTAL + (size_t)cblk * C_PER_BLK) * NBINS + tid;

    // ---- staging: plain loads -> registers -> ds_write_b128 ----
    float4 stg[MAXC];

    auto LOADQ = [&](int qd) {
        const float* f0 = fb + (size_t)qd * 4 * HW;
        const float* f1 = f0 + HW;
        const float* f2 = f1 + HW;
        const float* f3 = f2 + HW;
        #pragma unroll
        for (int s = 0; s < MAXC; ++s) {
            float4 v;
            v.x = f0[gw[s]];
            v.y = f1[gw[s]];
            v.z = f2[gw[s]];
            v.w = f3[gw[s]];
            stg[s] = v;
        }
    };
    auto WRITEQ = [&](float* dst) {
        #pragma unroll
        for (int s = 0; s < MAXC; ++s)
            if (cv[s]) *(float4*)(dst + lw[s]) = stg[s];
    };

    // ---- prologue: stage quad 0 into buffer 0; loads for quad 1 in flight ----
    LOADQ(0);
    WRITEQ(&tile[0][0]);
    LOADQ(1);

    // ---- quad loop: barrier -> compute(p) -> WRITEQ(p+1) [waits loads issued
    //      a full iteration earlier] -> issue LOADQ(p+2) -> store(p) ----
    for (int p = 0; p < NQUADS; ++p) {
        __syncthreads();   // stage(p) visible; all waves done reading buf (p+1)&1

        const float* bp = &tile[p & 1][0];
        float vx = 0.0f, vy = 0.0f, vz = 0.0f, vw = 0.0f;
        #pragma unroll
        for (int i = 0; i < 4; ++i) {
            const float4 t0 = *(const float4*)(bp + (wq[4*i + 0] << 2));
            const float4 t1 = *(const float4*)(bp + (wq[4*i + 1] << 2));
            const float4 t2 = *(const float4*)(bp + (wq[4*i + 2] << 2));
            const float4 t3 = *(const float4*)(bp + (wq[4*i + 3] << 2));
            const float wyi = wyv[i];
            vx += wyi * (wx0*t0.x + wx1*t1.x + wx2*t2.x + wx3*t3.x);
            vy += wyi * (wx0*t0.y + wx1*t1.y + wx2*t2.y + wx3*t3.y);
            vz += wyi * (wx0*t0.z + wx1*t1.z + wx2*t2.z + wx3*t3.z);
            vw += wyi * (wx0*t0.w + wx1*t1.w + wx2*t2.w + wx3*t3.w);
        }

        if (p + 1 < NQUADS) WRITEQ(&tile[(p + 1) & 1][0]);  // consumes stg(p+1)
        if (p + 2 < NQUADS) LOADQ(p + 2);                   // in flight until next iter's WRITEQ

        if (active) {
            ob[(size_t)(4*p + 0) * NBINS] = vx;
            ob[(size_t)(4*p + 1) * NBINS] = vy;
            ob[(size_t)(4*p + 2) * NBINS] = vz;
            ob[(size_t)(4*p + 3) * NBINS] = vw;
        }
    }
}

extern "C" void kernel_launch(void* const* d_in, const int* in_sizes, int n_in,
                              void* d_out, int out_size, void* d_ws, size_t ws_size,
                              hipStream_t stream) {
    const float* x0    = (const float*)d_in[0];
    const float* x1    = (const float*)d_in[1];
    const float* x2    = (const float*)d_in[2];
    const float* x3    = (const float*)d_in[3];
    const float* boxes = (const float*)d_in[4];
    float* out = (float*)d_out;

    dim3 grid(NBOXES, C_TOTAL / C_PER_BLK);
    dim3 block(256);
    roi_pool_kernel<<<grid, block, 0, stream>>>(x0, x1, x2, x3, boxes, out);
}

// Round 10
// 242.191 us; speedup vs baseline: 1.0169x; 1.0169x over previous
//
#include <hip/hip_runtime.h>
#include <stdint.h>

#define OUT_HW    14
#define NBINS     196               // 14*14
#define C_TOTAL   256
#define C_PER_BLK 64
#define NQUADS    (C_PER_BLK / 4)   // 16 channel-quads per block
#define NBOXES    512
#define BUFQ      1280              // 16B cells per buffer (strict footprint bound ~1016)
#define QWORDS    (4 * BUFQ)        // 5120 words = 20 KB per buffer (2 bufs = 40 KB)
#define MAXC      5                 // BUFQ / 256 cells per thread

__device__ __forceinline__ void axis_entry(float coord, float L,
                                           int& lo, int& hi, float& wlo, float& whi) {
    // torchvision ROIAlign bilinear edge handling
    const bool valid = (coord >= -1.0f) && (coord <= L);
    const float c   = fminf(fmaxf(coord, 0.0f), L - 1.0f);
    const float flo = floorf(c);
    const float fhi = fminf(flo + 1.0f, L - 1.0f);
    whi = c - flo;
    wlo = 1.0f - whi;
    if (!valid) { wlo = 0.0f; whi = 0.0f; }
    lo = (int)flo;
    hi = (int)fhi;
}

__global__ __launch_bounds__(256, 4) void roi_pool_kernel(
    const float* __restrict__ x0, const float* __restrict__ x1,
    const float* __restrict__ x2, const float* __restrict__ x3,
    const float* __restrict__ boxes, float* __restrict__ out)
{
    __shared__ float tile[2][QWORDS];   // 2 x 20 KB = 40 KB -> 4 blocks/CU

    const int m    = blockIdx.x;   // box
    const int cblk = blockIdx.y;   // 64-channel chunk
    const int tid  = threadIdx.x;

    // ---- block-uniform box/level setup ----
    const float bxi = boxes[m*5+0];
    const float bx0 = boxes[m*5+1];
    const float by0 = boxes[m*5+2];
    const float bx1 = boxes[m*5+3];
    const float by1 = boxes[m*5+4];

    const float sz = sqrtf((bx1 - bx0) * (by1 - by0));
    int lvl = (int)floorf(4.0f + log2f(sz * (1.0f/224.0f) + 1e-8f));
    lvl = min(max(lvl, 2), 5) - 2;

    const float scales[4] = {0.25f, 0.125f, 0.0625f, 0.03125f};
    const int   dims[4]   = {256, 128, 64, 32};
    const float scale = scales[lvl];
    const int   W  = dims[lvl];
    const int   HW = W * W;
    const float Lf = (float)W;
    const float* feat = (lvl == 0) ? x0 : (lvl == 1) ? x1 : (lvl == 2) ? x2 : x3;
    const int bidx = (int)bxi;

    const float rx0 = bx0*scale - 0.5f;
    const float ry0 = by0*scale - 0.5f;
    const float binw = (bx1*scale - 0.5f - rx0) * (1.0f/14.0f);
    const float binh = (by1*scale - 0.5f - ry0) * (1.0f/14.0f);

    // ---- footprint extents (samples are monotone; first lo / last hi) ----
    int ymin, ymax, xmin, xmax;
    {
        int lo, hi; float a, b;
        axis_entry(ry0 +  0.25f*binh, Lf, lo, hi, a, b); ymin = lo;
        axis_entry(ry0 + 13.75f*binh, Lf, lo, hi, a, b); ymax = hi;
        axis_entry(rx0 +  0.25f*binw, Lf, lo, hi, a, b); xmin = lo;
        axis_entry(rx0 + 13.75f*binw, Lf, lo, hi, a, b); xmax = hi;
    }
    const int TW = (xmax - xmin + 1) | 1;          // ODD cell stride: rotates bank phase per row
    int NR = ymax - ymin + 1;                      // tile rows
    if (NR * TW > BUFQ) NR = BUFQ / TW;            // safety cap (analysis: never triggers)
    const int TC = NR * TW;                        // cells (16B each) per quad tile

    // ---- per-thread cell slots (constant across quads); pure row-major layout ----
    int  gw[MAXC], lw[MAXC];
    bool cv[MAXC];
    #pragma unroll
    for (int s = 0; s < MAXC; ++s) {
        const int cell = tid + (s << 8);
        cv[s] = (cell < TC);
        const int cl = min(cell, TC - 1);
        const int r  = cl / TW;
        const int c  = cl - r * TW;
        gw[s] = min((ymin + r) * W + xmin + c, HW - 1);   // clamp: pad cols stay in-plane
        lw[s] = cl << 2;                                   // linear dest word (cell*4)
    }

    // ---- per-thread tap setup (bin = thread) ----
    const bool active = (tid < NBINS);
    const int  t  = active ? tid : (NBINS - 1);
    const int  ph = t / OUT_HW;
    const int  pw = t - ph * OUT_HW;

    int yl0, yh0, yl1, yh1, xl0, xh0, xl1, xh1;
    float wy0, wy1, wy2, wy3, wx0, wx1, wx2, wx3;
    axis_entry(ry0 + ((float)ph + 0.25f)*binh, Lf, yl0, yh0, wy0, wy1);
    axis_entry(ry0 + ((float)ph + 0.75f)*binh, Lf, yl1, yh1, wy2, wy3);
    axis_entry(rx0 + ((float)pw + 0.25f)*binw, Lf, xl0, xh0, wx0, wx1);
    axis_entry(rx0 + ((float)pw + 0.75f)*binw, Lf, xl1, xh1, wx2, wx3);
    wy0 *= 0.25f; wy1 *= 0.25f; wy2 *= 0.25f; wy3 *= 0.25f;  // fold 2x2 mean
    const float wyv[4] = { wy0, wy1, wy2, wy3 };

    const int sr[4] = { yl0 - ymin, yh0 - ymin, yl1 - ymin, yh1 - ymin };
    const int sc[4] = { xl0 - xmin, xh0 - xmin, xl1 - xmin, xh1 - xmin };

    int wq[16];   // tap cell indices (16B units), row-major
    #pragma unroll
    for (int i = 0; i < 4; ++i) {
        #pragma unroll
        for (int j = 0; j < 4; ++j) {
            wq[i*4 + j] = min(sr[i] * TW + sc[j], TC - 1);
        }
    }

    const float* fb = feat + ((size_t)bidx * C_TOTAL + (size_t)cblk * C_PER_BLK) * HW;
    float* ob = out + ((size_t)m * C_TOTAL + (size_t)cblk * C_PER_BLK) * NBINS + tid;

    // ---- staging: plain loads -> registers -> ds_write_b128 ----
    float4 stg[MAXC];

    auto LOADQ = [&](int qd) {
        const float* f0 = fb + (size_t)qd * 4 * HW;
        const float* f1 = f0 + HW;
        const float* f2 = f1 + HW;
        const float* f3 = f2 + HW;
        #pragma unroll
        for (int s = 0; s < MAXC; ++s) {
            float4 v;
            v.x = f0[gw[s]];
            v.y = f1[gw[s]];
            v.z = f2[gw[s]];
            v.w = f3[gw[s]];
            stg[s] = v;
        }
    };
    auto WRITEQ = [&](float* dst) {
        #pragma unroll
        for (int s = 0; s < MAXC; ++s)
            if (cv[s]) *(float4*)(dst + lw[s]) = stg[s];
    };

    // ---- prologue: stage quad 0 into buffer 0 ----
    LOADQ(0);
    WRITEQ(&tile[0][0]);

    // ---- quad loop: barrier -> issue loads(p+1) -> compute(p) -> write(p+1) ----
    // (round-8 proven schedule: stg live only across the compute phase, no spill)
    for (int p = 0; p < NQUADS; ++p) {
        __syncthreads();   // stage(p) visible; all waves done reading buf (p+1)&1
        const bool more = (p + 1 < NQUADS);
        if (more) LOADQ(p + 1);                 // HBM latency hides under compute below

        const float* bp = &tile[p & 1][0];
        float vx = 0.0f, vy = 0.0f, vz = 0.0f, vw = 0.0f;
        #pragma unroll
        for (int i = 0; i < 4; ++i) {
            const float4 t0 = *(const float4*)(bp + (wq[4*i + 0] << 2));
            const float4 t1 = *(const float4*)(bp + (wq[4*i + 1] << 2));
            const float4 t2 = *(const float4*)(bp + (wq[4*i + 2] << 2));
            const float4 t3 = *(const float4*)(bp + (wq[4*i + 3] << 2));
            const float wyi = wyv[i];
            vx += wyi * (wx0*t0.x + wx1*t1.x + wx2*t2.x + wx3*t3.x);
            vy += wyi * (wx0*t0.y + wx1*t1.y + wx2*t2.y + wx3*t3.y);
            vz += wyi * (wx0*t0.z + wx1*t1.z + wx2*t2.z + wx3*t3.z);
            vw += wyi * (wx0*t0.w + wx1*t1.w + wx2*t2.w + wx3*t3.w);
        }
        if (active) {
            ob[(size_t)(4*p + 0) * NBINS] = vx;
            ob[(size_t)(4*p + 1) * NBINS] = vy;
            ob[(size_t)(4*p + 2) * NBINS] = vz;
            ob[(size_t)(4*p + 3) * NBINS] = vw;
        }
        if (more) WRITEQ(&tile[(p + 1) & 1][0]);   // drained by the next barrier
    }
}

extern "C" void kernel_launch(void* const* d_in, const int* in_sizes, int n_in,
                              void* d_out, int out_size, void* d_ws, size_t ws_size,
                              hipStream_t stream) {
    const float* x0    = (const float*)d_in[0];
    const float* x1    = (const float*)d_in[1];
    const float* x2    = (const float*)d_in[2];
    const float* x3    = (const float*)d_in[3];
    const float* boxes = (const float*)d_in[4];
    float* out = (float*)d_out;

    dim3 grid(NBOXES, C_TOTAL / C_PER_BLK);
    dim3 block(256);
    roi_pool_kernel<<<grid, block, 0, stream>>>(x0, x1, x2, x3, boxes, out);
}

// Round 11
// 91.683 us; speedup vs baseline: 2.6861x; 2.6416x over previous
//
#include <hip/hip_runtime.h>
#include <stdint.h>

#define OUT_HW    14
#define NBINS     196               // 14*14
#define C_TOTAL   256
#define C_PER_BLK 64
#define NQUADS    (C_PER_BLK / 4)   // 16 channel-quads per block
#define NBOXES    512
#define BUFQ      1280              // 16B cells per buffer (strict footprint bound ~900)
#define QWORDS    (4 * BUFQ)        // 5120 words = 20 KB per buffer (2 bufs = 40 KB)
#define MAXC      5                 // BUFQ / 256 cells per thread

__device__ __forceinline__ void axis_entry(float coord, float L,
                                           int& lo, int& hi, float& wlo, float& whi) {
    // torchvision ROIAlign bilinear edge handling
    const bool valid = (coord >= -1.0f) && (coord <= L);
    const float c   = fminf(fmaxf(coord, 0.0f), L - 1.0f);
    const float flo = floorf(c);
    const float fhi = fminf(flo + 1.0f, L - 1.0f);
    whi = c - flo;
    wlo = 1.0f - whi;
    if (!valid) { wlo = 0.0f; whi = 0.0f; }
    lo = (int)flo;
    hi = (int)fhi;
}

// NOTE: __launch_bounds__(256, 3): (256,4) makes the allocator clamp to 64 VGPR
// (occupancy step) -> stg[] spills to scratch -> +300 MB FETCH, 2.4x slower
// (measured rounds 9/10). With (256,3) VGPR~84 <= 128, so HW can still run
// 4 blocks/CU (40 KB LDS, 84 VGPR both fit) -- the bound is a floor, not a cap.
__global__ __launch_bounds__(256, 3) void roi_pool_kernel(
    const float* __restrict__ x0, const float* __restrict__ x1,
    const float* __restrict__ x2, const float* __restrict__ x3,
    const float* __restrict__ boxes, float* __restrict__ out)
{
    __shared__ float tile[2][QWORDS];   // 2 x 20 KB = 40 KB -> 4 blocks/CU fit

    const int m    = blockIdx.x;   // box
    const int cblk = blockIdx.y;   // 64-channel chunk
    const int tid  = threadIdx.x;

    // ---- block-uniform box/level setup ----
    const float bxi = boxes[m*5+0];
    const float bx0 = boxes[m*5+1];
    const float by0 = boxes[m*5+2];
    const float bx1 = boxes[m*5+3];
    const float by1 = boxes[m*5+4];

    const float sz = sqrtf((bx1 - bx0) * (by1 - by0));
    int lvl = (int)floorf(4.0f + log2f(sz * (1.0f/224.0f) + 1e-8f));
    lvl = min(max(lvl, 2), 5) - 2;

    const float scales[4] = {0.25f, 0.125f, 0.0625f, 0.03125f};
    const int   dims[4]   = {256, 128, 64, 32};
    const float scale = scales[lvl];
    const int   W  = dims[lvl];
    const int   HW = W * W;
    const float Lf = (float)W;
    const float* feat = (lvl == 0) ? x0 : (lvl == 1) ? x1 : (lvl == 2) ? x2 : x3;
    const int bidx = (int)bxi;

    const float rx0 = bx0*scale - 0.5f;
    const float ry0 = by0*scale - 0.5f;
    const float binw = (bx1*scale - 0.5f - rx0) * (1.0f/14.0f);
    const float binh = (by1*scale - 0.5f - ry0) * (1.0f/14.0f);

    // ---- footprint extents (samples are monotone; first lo / last hi) ----
    int ymin, ymax, xmin, xmax;
    {
        int lo, hi; float a, b;
        axis_entry(ry0 +  0.25f*binh, Lf, lo, hi, a, b); ymin = lo;
        axis_entry(ry0 + 13.75f*binh, Lf, lo, hi, a, b); ymax = hi;
        axis_entry(rx0 +  0.25f*binw, Lf, lo, hi, a, b); xmin = lo;
        axis_entry(rx0 + 13.75f*binw, Lf, lo, hi, a, b); xmax = hi;
    }
    const int TW = (xmax - xmin + 1) | 1;          // ODD cell stride: rotates bank phase per row
    int NR = ymax - ymin + 1;                      // tile rows
    if (NR * TW > BUFQ) NR = BUFQ / TW;            // safety cap (analysis: never triggers)
    const int TC = NR * TW;                        // cells (16B each) per quad tile

    // ---- per-thread cell slots (constant across quads); pure row-major layout ----
    int  gw[MAXC], lw[MAXC];
    bool cv[MAXC];
    #pragma unroll
    for (int s = 0; s < MAXC; ++s) {
        const int cell = tid + (s << 8);
        cv[s] = (cell < TC);
        const int cl = min(cell, TC - 1);
        const int r  = cl / TW;
        const int c  = cl - r * TW;
        gw[s] = min((ymin + r) * W + xmin + c, HW - 1);   // clamp: pad cols stay in-plane
        lw[s] = cl << 2;                                   // linear dest word (cell*4)
    }

    // ---- per-thread tap setup (bin = thread) ----
    const bool active = (tid < NBINS);
    const int  t  = active ? tid : (NBINS - 1);
    const int  ph = t / OUT_HW;
    const int  pw = t - ph * OUT_HW;

    int yl0, yh0, yl1, yh1, xl0, xh0, xl1, xh1;
    float wy0, wy1, wy2, wy3, wx0, wx1, wx2, wx3;
    axis_entry(ry0 + ((float)ph + 0.25f)*binh, Lf, yl0, yh0, wy0, wy1);
    axis_entry(ry0 + ((float)ph + 0.75f)*binh, Lf, yl1, yh1, wy2, wy3);
    axis_entry(rx0 + ((float)pw + 0.25f)*binw, Lf, xl0, xh0, wx0, wx1);
    axis_entry(rx0 + ((float)pw + 0.75f)*binw, Lf, xl1, xh1, wx2, wx3);
    wy0 *= 0.25f; wy1 *= 0.25f; wy2 *= 0.25f; wy3 *= 0.25f;  // fold 2x2 mean
    const float wyv[4] = { wy0, wy1, wy2, wy3 };

    const int sr[4] = { yl0 - ymin, yh0 - ymin, yl1 - ymin, yh1 - ymin };
    const int sc[4] = { xl0 - xmin, xh0 - xmin, xl1 - xmin, xh1 - xmin };

    int wq[16];   // tap cell indices (16B units), row-major
    #pragma unroll
    for (int i = 0; i < 4; ++i) {
        #pragma unroll
        for (int j = 0; j < 4; ++j) {
            wq[i*4 + j] = min(sr[i] * TW + sc[j], TC - 1);
        }
    }

    const float* fb = feat + ((size_t)bidx * C_TOTAL + (size_t)cblk * C_PER_BLK) * HW;
    float* ob = out + ((size_t)m * C_TOTAL + (size_t)cblk * C_PER_BLK) * NBINS + tid;

    // ---- staging: plain loads -> registers -> ds_write_b128 ----
    float4 stg[MAXC];

    auto LOADQ = [&](int qd) {
        const float* f0 = fb + (size_t)qd * 4 * HW;
        const float* f1 = f0 + HW;
        const float* f2 = f1 + HW;
        const float* f3 = f2 + HW;
        #pragma unroll
        for (int s = 0; s < MAXC; ++s) {
            float4 v;
            v.x = f0[gw[s]];
            v.y = f1[gw[s]];
            v.z = f2[gw[s]];
            v.w = f3[gw[s]];
            stg[s] = v;
        }
    };
    auto WRITEQ = [&](float* dst) {
        #pragma unroll
        for (int s = 0; s < MAXC; ++s)
            if (cv[s]) *(float4*)(dst + lw[s]) = stg[s];
    };

    // ---- prologue: stage quad 0 into buffer 0 ----
    LOADQ(0);
    WRITEQ(&tile[0][0]);

    // ---- quad loop: barrier -> issue loads(p+1) -> compute(p) -> write(p+1) ----
    // (round-8 proven schedule: stg live only across the compute phase, no spill)
    for (int p = 0; p < NQUADS; ++p) {
        __syncthreads();   // stage(p) visible; all waves done reading buf (p+1)&1
        const bool more = (p + 1 < NQUADS);
        if (more) LOADQ(p + 1);                 // HBM latency hides under compute below

        const float* bp = &tile[p & 1][0];
        float vx = 0.0f, vy = 0.0f, vz = 0.0f, vw = 0.0f;
        #pragma unroll
        for (int i = 0; i < 4; ++i) {
            const float4 t0 = *(const float4*)(bp + (wq[4*i + 0] << 2));
            const float4 t1 = *(const float4*)(bp + (wq[4*i + 1] << 2));
            const float4 t2 = *(const float4*)(bp + (wq[4*i + 2] << 2));
            const float4 t3 = *(const float4*)(bp + (wq[4*i + 3] << 2));
            const float wyi = wyv[i];
            vx += wyi * (wx0*t0.x + wx1*t1.x + wx2*t2.x + wx3*t3.x);
            vy += wyi * (wx0*t0.y + wx1*t1.y + wx2*t2.y + wx3*t3.y);
            vz += wyi * (wx0*t0.z + wx1*t1.z + wx2*t2.z + wx3*t3.z);
            vw += wyi * (wx0*t0.w + wx1*t1.w + wx2*t2.w + wx3*t3.w);
        }
        if (active) {
            ob[(size_t)(4*p + 0) * NBINS] = vx;
            ob[(size_t)(4*p + 1) * NBINS] = vy;
            ob[(size_t)(4*p + 2) * NBINS] = vz;
            ob[(size_t)(4*p + 3) * NBINS] = vw;
        }
        if (more) WRITEQ(&tile[(p + 1) & 1][0]);   // drained by the next barrier
    }
}

extern "C" void kernel_launch(void* const* d_in, const int* in_sizes, int n_in,
                              void* d_out, int out_size, void* d_ws, size_t ws_size,
                              hipStream_t stream) {
    const float* x0    = (const float*)d_in[0];
    const float* x1    = (const float*)d_in[1];
    const float* x2    = (const float*)d_in[2];
    const float* x3    = (const float*)d_in[3];
    const float* boxes = (const float*)d_in[4];
    float* out = (float*)d_out;

    dim3 grid(NBOXES, C_TOTAL / C_PER_BLK);
    dim3 block(256);
    roi_pool_kernel<<<grid, block, 0, stream>>>(x0, x1, x2, x3, boxes, out);
}